// Round 12
// baseline (636.702 us; speedup 1.0000x reference)
//
#include <hip/hip_runtime.h>
#include <cstdint>
#include <cstddef>

typedef __attribute__((ext_vector_type(8))) _Float16 f16x8;
typedef __attribute__((ext_vector_type(4))) float f32x4;

#define B_ROWS 16384
#define K_DIM  1024
#define H_DIM  4096
#define O_DIM  4
#define NT     32              // K_DIM / 32 K-tiles
#define MARGIN 2.5e-3f         // 6.3 sigma of the f16 dot error (sigma~4e-4)
#define STASH_CAP 2048         // flags/block ~Poisson(40); 50x headroom

// ws layout (bytes)
#define OFF_XH   ((size_t)0)                 // 16384*1024*2 = 33554432
#define OFF_WH   ((size_t)33554432)          // 4096*1024*2  =  8388608
#define OFF_BITS ((size_t)41943040)          // 16384*128*4  =  8388608
#define WS_NEED  ((size_t)50331648)

#define GLD16(g, l) __builtin_amdgcn_global_load_lds(                         \
    (const __attribute__((address_space(1))) void*)(g),                       \
    (__attribute__((address_space(3))) void*)(l), 16, 0, 0)

// ---------------------------------------------------------------------------
// split: f32 -> f16 (RTN) for x and W1, fused.
// ---------------------------------------------------------------------------
__global__ __launch_bounds__(256) void split_f16(
    const float* __restrict__ x, const float* __restrict__ W1,
    _Float16* __restrict__ Xh, _Float16* __restrict__ Wh)
{
    const int NX8 = (B_ROWS * K_DIM) / 8;
    const int NW8 = (H_DIM * K_DIM) / 8;
    const int stride = gridDim.x * blockDim.x;
    for (int i = blockIdx.x * blockDim.x + threadIdx.x; i < NX8 + NW8; i += stride) {
        const float* src; _Float16* dst; int j;
        if (i < NX8) { src = x; dst = Xh; j = i; }
        else         { src = W1; dst = Wh; j = i - NX8; }
        const float4 f0 = reinterpret_cast<const float4*>(src)[2 * j];
        const float4 f1 = reinterpret_cast<const float4*>(src)[2 * j + 1];
        f16x8 h;
        h[0] = (_Float16)f0.x; h[1] = (_Float16)f0.y;
        h[2] = (_Float16)f0.z; h[3] = (_Float16)f0.w;
        h[4] = (_Float16)f1.x; h[5] = (_Float16)f1.y;
        h[6] = (_Float16)f1.z; h[7] = (_Float16)f1.w;
        reinterpret_cast<f16x8*>(dst)[j] = h;
    }
}

// ---------------------------------------------------------------------------
// fc1: f16 MFMA GEMM, 256x128 tile, BK=32, 8 waves (4M x 2N), 3-deep LDS
// ring with counted vmcnt(3). Conflict-free chunk-XOR swizzle. FUSED exact
// f64 refine epilogue. (r11 minus setprio, margin 2.5e-3.)
// ---------------------------------------------------------------------------
__global__ __launch_bounds__(512, 4) void fc1_f16(
    const _Float16* __restrict__ Xh, const _Float16* __restrict__ Wh,
    const float* __restrict__ xf, const float* __restrict__ w1f,
    const float* __restrict__ b1, uint32_t* __restrict__ bits)
{
    __shared__ __align__(16) _Float16 As[3][256 * 32];   // 48 KB
    __shared__ __align__(16) _Float16 Bs[3][128 * 32];   // 24 KB
    __shared__ uint32_t scnt;

    const int tid  = threadIdx.x;
    const int lane = tid & 63;
    const int w    = tid >> 6;                 // wave 0..7
    const int m0   = blockIdx.y * 256;
    const int n0   = blockIdx.x * 128;

    // staging: 8 waves x 16 rows = 128 rows per GLD16 call; A needs 2 calls,
    // B one. 16B chunk = (lane&3) XOR'd with (row>>1)&3 on the GLOBAL side
    // (LDS dest linear, rule 21). (+128 rows keeps the XOR index.)
    const int   srow   = w * 16 + (lane >> 2);            // 0..127
    const int   schunk = (((lane & 3) ^ ((srow >> 1) & 3)) << 3);  // halfs
    const size_t gA0 = (size_t)(m0 + srow) * K_DIM + schunk;
    const size_t gA1 = (size_t)(m0 + 128 + srow) * K_DIM + schunk;
    const size_t gB0 = (size_t)(n0 + srow) * K_DIM + schunk;

    auto stage = [&](int rb, int t) {        // 3 GLD16 per thread
        const int k0 = t * 32;
        GLD16(Xh + gA0 + k0, &As[rb][w * 512]);
        GLD16(Xh + gA1 + k0, &As[rb][4096 + w * 512]);
        GLD16(Wh + gB0 + k0, &Bs[rb][w * 512]);
    };

    const int wr   = (w >> 1) * 64;            // 0,64,128,192  (M group)
    const int wc   = (w & 1) * 64;             // 0,64          (N group)
    const int frow = lane & 15;
    const int rsw  = (((lane >> 4) ^ ((frow >> 1) & 3)) << 3);     // halfs

    f32x4 acc[4][4];
#pragma unroll
    for (int i = 0; i < 4; ++i)
#pragma unroll
        for (int j = 0; j < 4; ++j)
            acc[i][j] = (f32x4){0.f, 0.f, 0.f, 0.f};

    // prologue: tiles 0,1 in flight; wait tile 0 (3 newest = tile 1 stay out)
    stage(0, 0);
    stage(1, 1);
    asm volatile("s_waitcnt vmcnt(3)" ::: "memory");
    __builtin_amdgcn_s_barrier();

    int cur = 0, s2 = 2;
    for (int t = 0; t < NT; ++t) {
        if (t + 2 < NT) stage(s2, t + 2);      // issue ahead
        f16x8 a[4], b[4];
#pragma unroll
        for (int mi = 0; mi < 4; ++mi)
            a[mi] = *reinterpret_cast<const f16x8*>(
                &As[cur][(wr + mi * 16 + frow) * 32 + rsw]);
#pragma unroll
        for (int nj = 0; nj < 4; ++nj)
            b[nj] = *reinterpret_cast<const f16x8*>(
                &Bs[cur][(wc + nj * 16 + frow) * 32 + rsw]);
#pragma unroll
        for (int mi = 0; mi < 4; ++mi)
#pragma unroll
            for (int nj = 0; nj < 4; ++nj)
                acc[mi][nj] = __builtin_amdgcn_mfma_f32_16x16x32_f16(
                    a[mi], b[nj], acc[mi][nj], 0, 0, 0);
        asm volatile("s_waitcnt lgkmcnt(0)" ::: "memory");   // WAR: slot reuse
        if (t + 2 < NT) { asm volatile("s_waitcnt vmcnt(3)" ::: "memory"); }
        else            { asm volatile("s_waitcnt vmcnt(0)" ::: "memory"); }
        __builtin_amdgcn_s_barrier();
        cur = (cur == 2) ? 0 : cur + 1;
        s2  = (s2  == 2) ? 0 : s2  + 1;
    }

    // ---- epilogue pass 1: ballot words -> LDS bitbuf, flags -> LDS stash ----
    __syncthreads();                           // staged data dead; reuse LDS
    uint32_t* stash  = (uint32_t*)&As[0][0];   // up to STASH_CAP entries
    uint32_t* bitbuf = (uint32_t*)&Bs[0][0];   // 256 rows x 4 words = 4 KB
    if (tid == 0) scnt = 0u;
    __syncthreads();

    float bcol[4];
#pragma unroll
    for (int nj = 0; nj < 4; ++nj) bcol[nj] = b1[n0 + wc + nj * 16 + frow];

    const int g = lane >> 4;
#pragma unroll
    for (int mi = 0; mi < 4; ++mi) {
#pragma unroll
        for (int r = 0; r < 4; ++r) {
            unsigned long long bj[4];
#pragma unroll
            for (int nj = 0; nj < 4; ++nj) {
                const float cur_v = acc[mi][nj][r] + bcol[nj];
                bj[nj] = __ballot(cur_v > 1.0f);
                if (fabsf(cur_v - 1.0f) < MARGIN) {
                    const uint32_t enc =
                        ((uint32_t)(wr + mi * 16 + g * 4 + r) << 7)
                      | (uint32_t)(wc + nj * 16 + frow);
                    uint32_t ix = atomicAdd(&scnt, 1u);
                    if (ix < STASH_CAP) stash[ix] = enc;
                }
            }
            if (frow == 0) {
                const int row_l = wr + mi * 16 + g * 4 + r;   // 0..255
                const uint32_t w0 =
                    (uint32_t)((bj[0] >> (g * 16)) & 0xFFFFull) |
                    ((uint32_t)((bj[1] >> (g * 16)) & 0xFFFFull) << 16);
                const uint32_t w1 =
                    (uint32_t)((bj[2] >> (g * 16)) & 0xFFFFull) |
                    ((uint32_t)((bj[3] >> (g * 16)) & 0xFFFFull) << 16);
                uint2 v; v.x = w0; v.y = w1;
                *reinterpret_cast<uint2*>(&bitbuf[row_l * 4 + (wc >> 5)]) = v;
            }
        }
    }
    __syncthreads();

    // ---- epilogue pass 2: in-block exact f64 refine (wave per flag) ----
    const uint32_t nf = (scnt < STASH_CAP) ? scnt : STASH_CAP;
    for (uint32_t f = (uint32_t)w; f < nf; f += 8) {
        const uint32_t e = stash[f];
        const int row_l = (int)(e >> 7), col_l = (int)(e & 127);
        const float4* xr  = (const float4*)(xf  + (size_t)(m0 + row_l) * K_DIM);
        const float4* wr2 = (const float4*)(w1f + (size_t)(n0 + col_l) * K_DIM);
        double s = 0.0;
#pragma unroll
        for (int i = 0; i < 4; ++i) {
            const float4 xa = xr[lane + i * 64];
            const float4 wa = wr2[lane + i * 64];
            s = fma((double)xa.x, (double)wa.x, s);
            s = fma((double)xa.y, (double)wa.y, s);
            s = fma((double)xa.z, (double)wa.z, s);
            s = fma((double)xa.w, (double)wa.w, s);
        }
        for (int off = 32; off; off >>= 1) s += __shfl_down(s, off, 64);
        if (lane == 0) {
            const double cur_v = s + (double)b1[n0 + col_l];
            uint32_t* word = &bitbuf[row_l * 4 + (col_l >> 5)];
            const uint32_t mask = 1u << (col_l & 31);
            if (cur_v > 1.0) atomicOr(word, mask);
            else             atomicAnd(word, ~mask);
        }
    }
    __syncthreads();

    // ---- epilogue pass 3: coalesced store, each word exactly once ----
    if (tid < 256) {
        const uint4 v = *reinterpret_cast<const uint4*>(&bitbuf[tid * 4]);
        *reinterpret_cast<uint4*>(
            &bits[(size_t)(m0 + tid) * 128 + (n0 >> 5)]) = v;
    }
}

// ---------------------------------------------------------------------------
// fc2: one wave per 8 batch rows (W2 loads reused 8x); f64 exact select-add.
// ---------------------------------------------------------------------------
__global__ __launch_bounds__(256) void fc2w8(
    const uint32_t* __restrict__ bits, const float* __restrict__ W2,
    const float* __restrict__ b2, float* __restrict__ out)
{
    const int lane = threadIdx.x & 63;
    const int rb   = (blockIdx.x * 4 + (threadIdx.x >> 6)) * 8;  // row base
    uint32_t w0[8], w1[8];
#pragma unroll
    for (int rr = 0; rr < 8; ++rr) {
        const uint2 v = *reinterpret_cast<const uint2*>(
            &bits[(size_t)(rb + rr) * 128 + 2 * lane]);
        w0[rr] = v.x; w1[rr] = v.y;
    }
    double acc[8][4];                          // [row][output]
#pragma unroll
    for (int rr = 0; rr < 8; ++rr)
#pragma unroll
        for (int o = 0; o < 4; ++o) acc[rr][o] = 0.0;

#pragma unroll
    for (int o = 0; o < 4; ++o) {
        const float4* wrow = (const float4*)(W2 + (size_t)o * H_DIM + lane * 64);
#pragma unroll
        for (int q = 0; q < 16; ++q) {
            const float4 v = wrow[q];
            const int bit = (4 * q) & 31;
#pragma unroll
            for (int rr = 0; rr < 8; ++rr) {
                const uint32_t word = (q < 8) ? w0[rr] : w1[rr];
                if ((word >> bit)       & 1u) acc[rr][o] += (double)v.x;
                if ((word >> (bit + 1)) & 1u) acc[rr][o] += (double)v.y;
                if ((word >> (bit + 2)) & 1u) acc[rr][o] += (double)v.z;
                if ((word >> (bit + 3)) & 1u) acc[rr][o] += (double)v.w;
            }
        }
    }
#pragma unroll
    for (int off = 32; off; off >>= 1)
#pragma unroll
        for (int rr = 0; rr < 8; ++rr)
#pragma unroll
            for (int o = 0; o < 4; ++o)
                acc[rr][o] += __shfl_down(acc[rr][o], off, 64);
    if (lane == 0) {
#pragma unroll
        for (int rr = 0; rr < 8; ++rr)
#pragma unroll
            for (int o = 0; o < 4; ++o) {
                const double cur = acc[rr][o] + (double)b2[o];
                out[(rb + rr) * 4 + o] = (float)cur;
                out[B_ROWS * O_DIM + (rb + rr) * 4 + o] = (cur > 1.0) ? 1.0f : 0.0f;
            }
    }
}

// ---------------------------------------------------------------------------
// Fallback exact-f64 fc1 (round-1 kernel) for small ws_size
// ---------------------------------------------------------------------------
#define BM 64
#define BN 64
#define BK 32
__global__ __launch_bounds__(256) void snn_fc1(
    const float* __restrict__ x, const float* __restrict__ W1,
    const float* __restrict__ b1, uint32_t* __restrict__ spk_bits)
{
    __shared__ float As[BK][68];
    __shared__ float Bs[BK][68];
    __shared__ uint32_t bitbuf[BM][BN / 32];

    const int tid = threadIdx.x;
    const int m0 = blockIdx.y * BM;
    const int n0 = blockIdx.x * BN;
    const int rm = tid & 15, cn = tid >> 4;
    const int mf = 4 * rm, nf = 4 * cn;

    double acc[4][4];
#pragma unroll
    for (int i = 0; i < 4; ++i)
#pragma unroll
        for (int j = 0; j < 4; ++j) acc[i][j] = 0.0;

    const int sm = tid >> 3, skq = tid & 7;
    for (int kt = 0; kt < K_DIM / BK; ++kt) {
        const int k0 = kt * BK;
#pragma unroll
        for (int s = 0; s < 2; ++s) {
            const int m = sm + 32 * s;
            const float4 av = *reinterpret_cast<const float4*>(
                x + (size_t)(m0 + m) * K_DIM + k0 + 4 * skq);
            As[4 * skq + 0][m] = av.x; As[4 * skq + 1][m] = av.y;
            As[4 * skq + 2][m] = av.z; As[4 * skq + 3][m] = av.w;
            const float4 bv = *reinterpret_cast<const float4*>(
                W1 + (size_t)(n0 + m) * K_DIM + k0 + 4 * skq);
            Bs[4 * skq + 0][m] = bv.x; Bs[4 * skq + 1][m] = bv.y;
            Bs[4 * skq + 2][m] = bv.z; Bs[4 * skq + 3][m] = bv.w;
        }
        __syncthreads();
#pragma unroll
        for (int k = 0; k < BK; ++k) {
            const float4 af = *reinterpret_cast<const float4*>(&As[k][mf]);
            const float4 bf = *reinterpret_cast<const float4*>(&Bs[k][nf]);
            const double a0 = af.x, a1 = af.y, a2 = af.z, a3 = af.w;
            const double b0 = bf.x, b1v = bf.y, b2v = bf.z, b3 = bf.w;
            acc[0][0] = fma(a0, b0, acc[0][0]);  acc[0][1] = fma(a0, b1v, acc[0][1]);
            acc[0][2] = fma(a0, b2v, acc[0][2]); acc[0][3] = fma(a0, b3, acc[0][3]);
            acc[1][0] = fma(a1, b0, acc[1][0]);  acc[1][1] = fma(a1, b1v, acc[1][1]);
            acc[1][2] = fma(a1, b2v, acc[1][2]); acc[1][3] = fma(a1, b3, acc[1][3]);
            acc[2][0] = fma(a2, b0, acc[2][0]);  acc[2][1] = fma(a2, b1v, acc[2][1]);
            acc[2][2] = fma(a2, b2v, acc[2][2]); acc[2][3] = fma(a2, b3, acc[2][3]);
            acc[3][0] = fma(a3, b0, acc[3][0]);  acc[3][1] = fma(a3, b1v, acc[3][1]);
            acc[3][2] = fma(a3, b2v, acc[3][2]); acc[3][3] = fma(a3, b3, acc[3][3]);
        }
        __syncthreads();
    }

    if (tid < BM * (BN / 32)) bitbuf[tid >> 1][tid & 1] = 0u;
    __syncthreads();
#pragma unroll
    for (int j = 0; j < 4; ++j) {
        const int n = nf + j;
        const double bias = (double)b1[n0 + n];
        const int wd = n >> 5, bit = n & 31;
#pragma unroll
        for (int i = 0; i < 4; ++i) {
            const double cur = acc[i][j] + bias;
            if (cur > 1.0) atomicOr(&bitbuf[mf + i][wd], 1u << bit);
        }
    }
    __syncthreads();
    if (tid < 128) {
        const int r = tid >> 1, wd = tid & 1;
        spk_bits[(size_t)(m0 + r) * (H_DIM / 32) + (n0 >> 5) + wd] = bitbuf[r][wd];
    }
}

// ---------------------------------------------------------------------------
extern "C" void kernel_launch(void* const* d_in, const int* in_sizes, int n_in,
                              void* d_out, int out_size, void* d_ws, size_t ws_size,
                              hipStream_t stream) {
    const float* x  = (const float*)d_in[0];
    const float* W1 = (const float*)d_in[1];
    const float* b1 = (const float*)d_in[2];
    const float* W2 = (const float*)d_in[3];
    const float* b2 = (const float*)d_in[4];
    float* out = (float*)d_out;
    char* ws = (char*)d_ws;

    if (ws_size >= WS_NEED) {
        _Float16* Xh   = (_Float16*)(ws + OFF_XH);
        _Float16* Wh   = (_Float16*)(ws + OFF_WH);
        uint32_t* bits = (uint32_t*)(ws + OFF_BITS);

        split_f16<<<4096, 256, 0, stream>>>(x, W1, Xh, Wh);
        fc1_f16<<<dim3(H_DIM / 128, B_ROWS / 256), 512, 0, stream>>>(
            Xh, Wh, x, W1, b1, bits);
        fc2w8<<<B_ROWS / 32, 256, 0, stream>>>(bits, W2, b2, out);
    } else {
        uint32_t* bits = (uint32_t*)ws;
        dim3 g1(H_DIM / BN, B_ROWS / BM);
        snn_fc1<<<g1, 256, 0, stream>>>(x, W1, b1, bits);
        fc2w8<<<B_ROWS / 32, 256, 0, stream>>>(bits, W2, b2, out);
    }
}

// Round 13
// 263.627 us; speedup vs baseline: 2.4152x; 2.4152x over previous
//
#include <hip/hip_runtime.h>
#include <cstdint>
#include <cstddef>

typedef __attribute__((ext_vector_type(8))) _Float16 f16x8;
typedef __attribute__((ext_vector_type(4))) float f32x4;

#define B_ROWS 16384
#define K_DIM  1024
#define H_DIM  4096
#define O_DIM  4
#define NT     32              // K_DIM / 32 K-tiles
#define MARGIN 2.5e-3f         // 6.3 sigma of the f16 dot error (sigma~4e-4)
#define STASH_CAP 2048         // flags/block ~Poisson(40); 50x headroom

// ws layout (bytes)
#define OFF_XH   ((size_t)0)                 // 16384*1024*2 = 33554432
#define OFF_WH   ((size_t)33554432)          // 4096*1024*2  =  8388608
#define OFF_BITS ((size_t)41943040)          // 16384*128*4  =  8388608
#define WS_NEED  ((size_t)50331648)

#define GLD16(g, l) __builtin_amdgcn_global_load_lds(                         \
    (const __attribute__((address_space(1))) void*)(g),                       \
    (__attribute__((address_space(3))) void*)(l), 16, 0, 0)

// ---------------------------------------------------------------------------
// split: f32 -> f16 (RTN) for x and W1, fused.
// ---------------------------------------------------------------------------
__global__ __launch_bounds__(256) void split_f16(
    const float* __restrict__ x, const float* __restrict__ W1,
    _Float16* __restrict__ Xh, _Float16* __restrict__ Wh)
{
    const int NX8 = (B_ROWS * K_DIM) / 8;
    const int NW8 = (H_DIM * K_DIM) / 8;
    const int stride = gridDim.x * blockDim.x;
    for (int i = blockIdx.x * blockDim.x + threadIdx.x; i < NX8 + NW8; i += stride) {
        const float* src; _Float16* dst; int j;
        if (i < NX8) { src = x; dst = Xh; j = i; }
        else         { src = W1; dst = Wh; j = i - NX8; }
        const float4 f0 = reinterpret_cast<const float4*>(src)[2 * j];
        const float4 f1 = reinterpret_cast<const float4*>(src)[2 * j + 1];
        f16x8 h;
        h[0] = (_Float16)f0.x; h[1] = (_Float16)f0.y;
        h[2] = (_Float16)f0.z; h[3] = (_Float16)f0.w;
        h[4] = (_Float16)f1.x; h[5] = (_Float16)f1.y;
        h[6] = (_Float16)f1.z; h[7] = (_Float16)f1.w;
        reinterpret_cast<f16x8*>(dst)[j] = h;
    }
}

// ---------------------------------------------------------------------------
// fc1: f16 MFMA GEMM, 256x128 tile, BK=32, 8 waves (4M x 2N), 3-deep LDS
// ring with counted vmcnt(3). Conflict-free chunk-XOR swizzle. FUSED exact
// f64 refine epilogue.
// ---------------------------------------------------------------------------
__global__ __launch_bounds__(512, 4) void fc1_f16(
    const _Float16* __restrict__ Xh, const _Float16* __restrict__ Wh,
    const float* __restrict__ xf, const float* __restrict__ w1f,
    const float* __restrict__ b1, uint32_t* __restrict__ bits)
{
    __shared__ __align__(16) _Float16 As[3][256 * 32];   // 48 KB
    __shared__ __align__(16) _Float16 Bs[3][128 * 32];   // 24 KB
    __shared__ uint32_t scnt;

    const int tid  = threadIdx.x;
    const int lane = tid & 63;
    const int w    = tid >> 6;                 // wave 0..7
    const int m0   = blockIdx.y * 256;
    const int n0   = blockIdx.x * 128;

    // staging: 8 waves x 16 rows = 128 rows per GLD16 call; A needs 2 calls,
    // B one. 16B chunk = (lane&3) XOR'd with (row>>1)&3 on the GLOBAL side
    // (LDS dest linear, rule 21). (+128 rows keeps the XOR index.)
    const int   srow   = w * 16 + (lane >> 2);            // 0..127
    const int   schunk = (((lane & 3) ^ ((srow >> 1) & 3)) << 3);  // halfs
    const size_t gA0 = (size_t)(m0 + srow) * K_DIM + schunk;
    const size_t gA1 = (size_t)(m0 + 128 + srow) * K_DIM + schunk;
    const size_t gB0 = (size_t)(n0 + srow) * K_DIM + schunk;

    auto stage = [&](int rb, int t) {        // 3 GLD16 per thread
        const int k0 = t * 32;
        GLD16(Xh + gA0 + k0, &As[rb][w * 512]);
        GLD16(Xh + gA1 + k0, &As[rb][4096 + w * 512]);
        GLD16(Wh + gB0 + k0, &Bs[rb][w * 512]);
    };

    const int wr   = (w >> 1) * 64;            // 0,64,128,192  (M group)
    const int wc   = (w & 1) * 64;             // 0,64          (N group)
    const int frow = lane & 15;
    const int rsw  = (((lane >> 4) ^ ((frow >> 1) & 3)) << 3);     // halfs

    f32x4 acc[4][4];
#pragma unroll
    for (int i = 0; i < 4; ++i)
#pragma unroll
        for (int j = 0; j < 4; ++j)
            acc[i][j] = (f32x4){0.f, 0.f, 0.f, 0.f};

    // prologue: tiles 0,1 in flight; wait tile 0 (3 newest = tile 1 stay out)
    stage(0, 0);
    stage(1, 1);
    asm volatile("s_waitcnt vmcnt(3)" ::: "memory");
    __builtin_amdgcn_s_barrier();

    int cur = 0, s2 = 2;
    for (int t = 0; t < NT; ++t) {
        if (t + 2 < NT) stage(s2, t + 2);      // issue ahead
        f16x8 a[4], b[4];
#pragma unroll
        for (int mi = 0; mi < 4; ++mi)
            a[mi] = *reinterpret_cast<const f16x8*>(
                &As[cur][(wr + mi * 16 + frow) * 32 + rsw]);
#pragma unroll
        for (int nj = 0; nj < 4; ++nj)
            b[nj] = *reinterpret_cast<const f16x8*>(
                &Bs[cur][(wc + nj * 16 + frow) * 32 + rsw]);
#pragma unroll
        for (int mi = 0; mi < 4; ++mi)
#pragma unroll
            for (int nj = 0; nj < 4; ++nj)
                acc[mi][nj] = __builtin_amdgcn_mfma_f32_16x16x32_f16(
                    a[mi], b[nj], acc[mi][nj], 0, 0, 0);
        asm volatile("s_waitcnt lgkmcnt(0)" ::: "memory");   // WAR: slot reuse
        if (t + 2 < NT) { asm volatile("s_waitcnt vmcnt(3)" ::: "memory"); }
        else            { asm volatile("s_waitcnt vmcnt(0)" ::: "memory"); }
        __builtin_amdgcn_s_barrier();
        cur = (cur == 2) ? 0 : cur + 1;
        s2  = (s2  == 2) ? 0 : s2  + 1;
    }

    // ---- epilogue pass 1: ballot words -> LDS bitbuf, flags -> LDS stash ----
    __syncthreads();                           // staged data dead; reuse LDS
    uint32_t* stash  = (uint32_t*)&As[0][0];   // up to STASH_CAP entries
    uint32_t* bitbuf = (uint32_t*)&Bs[0][0];   // 256 rows x 4 words = 4 KB
    if (tid == 0) scnt = 0u;
    __syncthreads();

    float bcol[4];
#pragma unroll
    for (int nj = 0; nj < 4; ++nj) bcol[nj] = b1[n0 + wc + nj * 16 + frow];

    const int g = lane >> 4;
#pragma unroll
    for (int mi = 0; mi < 4; ++mi) {
#pragma unroll
        for (int r = 0; r < 4; ++r) {
            unsigned long long bj[4];
#pragma unroll
            for (int nj = 0; nj < 4; ++nj) {
                const float cur_v = acc[mi][nj][r] + bcol[nj];
                bj[nj] = __ballot(cur_v > 1.0f);
                if (fabsf(cur_v - 1.0f) < MARGIN) {
                    const uint32_t enc =
                        ((uint32_t)(wr + mi * 16 + g * 4 + r) << 7)
                      | (uint32_t)(wc + nj * 16 + frow);
                    uint32_t ix = atomicAdd(&scnt, 1u);
                    if (ix < STASH_CAP) stash[ix] = enc;
                }
            }
            if (frow == 0) {
                const int row_l = wr + mi * 16 + g * 4 + r;   // 0..255
                const uint32_t w0 =
                    (uint32_t)((bj[0] >> (g * 16)) & 0xFFFFull) |
                    ((uint32_t)((bj[1] >> (g * 16)) & 0xFFFFull) << 16);
                const uint32_t w1 =
                    (uint32_t)((bj[2] >> (g * 16)) & 0xFFFFull) |
                    ((uint32_t)((bj[3] >> (g * 16)) & 0xFFFFull) << 16);
                uint2 v; v.x = w0; v.y = w1;
                *reinterpret_cast<uint2*>(&bitbuf[row_l * 4 + (wc >> 5)]) = v;
            }
        }
    }
    __syncthreads();

    // ---- epilogue pass 2: in-block exact f64 refine (wave per flag) ----
    const uint32_t nf = (scnt < STASH_CAP) ? scnt : STASH_CAP;
    for (uint32_t f = (uint32_t)w; f < nf; f += 8) {
        const uint32_t e = stash[f];
        const int row_l = (int)(e >> 7), col_l = (int)(e & 127);
        const float4* xr  = (const float4*)(xf  + (size_t)(m0 + row_l) * K_DIM);
        const float4* wr2 = (const float4*)(w1f + (size_t)(n0 + col_l) * K_DIM);
        double s = 0.0;
#pragma unroll
        for (int i = 0; i < 4; ++i) {
            const float4 xa = xr[lane + i * 64];
            const float4 wa = wr2[lane + i * 64];
            s = fma((double)xa.x, (double)wa.x, s);
            s = fma((double)xa.y, (double)wa.y, s);
            s = fma((double)xa.z, (double)wa.z, s);
            s = fma((double)xa.w, (double)wa.w, s);
        }
        for (int off = 32; off; off >>= 1) s += __shfl_down(s, off, 64);
        if (lane == 0) {
            const double cur_v = s + (double)b1[n0 + col_l];
            uint32_t* word = &bitbuf[row_l * 4 + (col_l >> 5)];
            const uint32_t mask = 1u << (col_l & 31);
            if (cur_v > 1.0) atomicOr(word, mask);
            else             atomicAnd(word, ~mask);
        }
    }
    __syncthreads();

    // ---- epilogue pass 3: coalesced store, each word exactly once ----
    if (tid < 256) {
        const uint4 v = *reinterpret_cast<const uint4*>(&bitbuf[tid * 4]);
        *reinterpret_cast<uint4*>(
            &bits[(size_t)(m0 + tid) * 128 + (n0 >> 5)]) = v;
    }
}

// ---------------------------------------------------------------------------
// fc2: one wave per 4 batch rows (W2 loads reused 4x, fits registers);
// f64 exact select-add. (r11 version — 8-row variant spilled to scratch.)
// ---------------------------------------------------------------------------
__global__ __launch_bounds__(256) void fc2w4(
    const uint32_t* __restrict__ bits, const float* __restrict__ W2,
    const float* __restrict__ b2, float* __restrict__ out)
{
    const int lane = threadIdx.x & 63;
    const int rb   = (blockIdx.x * 4 + (threadIdx.x >> 6)) * 4;  // row base
    uint32_t w0[4], w1[4];
#pragma unroll
    for (int rr = 0; rr < 4; ++rr) {
        const uint2 v = *reinterpret_cast<const uint2*>(
            &bits[(size_t)(rb + rr) * 128 + 2 * lane]);
        w0[rr] = v.x; w1[rr] = v.y;
    }
    double acc[4][4];                          // [row][output]
#pragma unroll
    for (int rr = 0; rr < 4; ++rr)
#pragma unroll
        for (int o = 0; o < 4; ++o) acc[rr][o] = 0.0;

#pragma unroll
    for (int o = 0; o < 4; ++o) {
        const float4* wrow = (const float4*)(W2 + (size_t)o * H_DIM + lane * 64);
#pragma unroll
        for (int q = 0; q < 16; ++q) {
            const float4 v = wrow[q];
            const int bit = (4 * q) & 31;
#pragma unroll
            for (int rr = 0; rr < 4; ++rr) {
                const uint32_t word = (q < 8) ? w0[rr] : w1[rr];
                if ((word >> bit)       & 1u) acc[rr][o] += (double)v.x;
                if ((word >> (bit + 1)) & 1u) acc[rr][o] += (double)v.y;
                if ((word >> (bit + 2)) & 1u) acc[rr][o] += (double)v.z;
                if ((word >> (bit + 3)) & 1u) acc[rr][o] += (double)v.w;
            }
        }
    }
#pragma unroll
    for (int off = 32; off; off >>= 1)
#pragma unroll
        for (int rr = 0; rr < 4; ++rr)
#pragma unroll
            for (int o = 0; o < 4; ++o)
                acc[rr][o] += __shfl_down(acc[rr][o], off, 64);
    if (lane == 0) {
#pragma unroll
        for (int rr = 0; rr < 4; ++rr)
#pragma unroll
            for (int o = 0; o < 4; ++o) {
                const double cur = acc[rr][o] + (double)b2[o];
                out[(rb + rr) * 4 + o] = (float)cur;
                out[B_ROWS * O_DIM + (rb + rr) * 4 + o] = (cur > 1.0) ? 1.0f : 0.0f;
            }
    }
}

// ---------------------------------------------------------------------------
// Fallback exact-f64 fc1 (round-1 kernel) for small ws_size
// ---------------------------------------------------------------------------
#define BM 64
#define BN 64
#define BK 32
__global__ __launch_bounds__(256) void snn_fc1(
    const float* __restrict__ x, const float* __restrict__ W1,
    const float* __restrict__ b1, uint32_t* __restrict__ spk_bits)
{
    __shared__ float As[BK][68];
    __shared__ float Bs[BK][68];
    __shared__ uint32_t bitbuf[BM][BN / 32];

    const int tid = threadIdx.x;
    const int m0 = blockIdx.y * BM;
    const int n0 = blockIdx.x * BN;
    const int rm = tid & 15, cn = tid >> 4;
    const int mf = 4 * rm, nf = 4 * cn;

    double acc[4][4];
#pragma unroll
    for (int i = 0; i < 4; ++i)
#pragma unroll
        for (int j = 0; j < 4; ++j) acc[i][j] = 0.0;

    const int sm = tid >> 3, skq = tid & 7;
    for (int kt = 0; kt < K_DIM / BK; ++kt) {
        const int k0 = kt * BK;
#pragma unroll
        for (int s = 0; s < 2; ++s) {
            const int m = sm + 32 * s;
            const float4 av = *reinterpret_cast<const float4*>(
                x + (size_t)(m0 + m) * K_DIM + k0 + 4 * skq);
            As[4 * skq + 0][m] = av.x; As[4 * skq + 1][m] = av.y;
            As[4 * skq + 2][m] = av.z; As[4 * skq + 3][m] = av.w;
            const float4 bv = *reinterpret_cast<const float4*>(
                W1 + (size_t)(n0 + m) * K_DIM + k0 + 4 * skq);
            Bs[4 * skq + 0][m] = bv.x; Bs[4 * skq + 1][m] = bv.y;
            Bs[4 * skq + 2][m] = bv.z; Bs[4 * skq + 3][m] = bv.w;
        }
        __syncthreads();
#pragma unroll
        for (int k = 0; k < BK; ++k) {
            const float4 af = *reinterpret_cast<const float4*>(&As[k][mf]);
            const float4 bf = *reinterpret_cast<const float4*>(&Bs[k][nf]);
            const double a0 = af.x, a1 = af.y, a2 = af.z, a3 = af.w;
            const double b0 = bf.x, b1v = bf.y, b2v = bf.z, b3 = bf.w;
            acc[0][0] = fma(a0, b0, acc[0][0]);  acc[0][1] = fma(a0, b1v, acc[0][1]);
            acc[0][2] = fma(a0, b2v, acc[0][2]); acc[0][3] = fma(a0, b3, acc[0][3]);
            acc[1][0] = fma(a1, b0, acc[1][0]);  acc[1][1] = fma(a1, b1v, acc[1][1]);
            acc[1][2] = fma(a1, b2v, acc[1][2]); acc[1][3] = fma(a1, b3, acc[1][3]);
            acc[2][0] = fma(a2, b0, acc[2][0]);  acc[2][1] = fma(a2, b1v, acc[2][1]);
            acc[2][2] = fma(a2, b2v, acc[2][2]); acc[2][3] = fma(a2, b3, acc[2][3]);
            acc[3][0] = fma(a3, b0, acc[3][0]);  acc[3][1] = fma(a3, b1v, acc[3][1]);
            acc[3][2] = fma(a3, b2v, acc[3][2]); acc[3][3] = fma(a3, b3, acc[3][3]);
        }
        __syncthreads();
    }

    if (tid < BM * (BN / 32)) bitbuf[tid >> 1][tid & 1] = 0u;
    __syncthreads();
#pragma unroll
    for (int j = 0; j < 4; ++j) {
        const int n = nf + j;
        const double bias = (double)b1[n0 + n];
        const int wd = n >> 5, bit = n & 31;
#pragma unroll
        for (int i = 0; i < 4; ++i) {
            const double cur = acc[i][j] + bias;
            if (cur > 1.0) atomicOr(&bitbuf[mf + i][wd], 1u << bit);
        }
    }
    __syncthreads();
    if (tid < 128) {
        const int r = tid >> 1, wd = tid & 1;
        spk_bits[(size_t)(m0 + r) * (H_DIM / 32) + (n0 >> 5) + wd] = bitbuf[r][wd];
    }
}

// ---------------------------------------------------------------------------
extern "C" void kernel_launch(void* const* d_in, const int* in_sizes, int n_in,
                              void* d_out, int out_size, void* d_ws, size_t ws_size,
                              hipStream_t stream) {
    const float* x  = (const float*)d_in[0];
    const float* W1 = (const float*)d_in[1];
    const float* b1 = (const float*)d_in[2];
    const float* W2 = (const float*)d_in[3];
    const float* b2 = (const float*)d_in[4];
    float* out = (float*)d_out;
    char* ws = (char*)d_ws;

    if (ws_size >= WS_NEED) {
        _Float16* Xh   = (_Float16*)(ws + OFF_XH);
        _Float16* Wh   = (_Float16*)(ws + OFF_WH);
        uint32_t* bits = (uint32_t*)(ws + OFF_BITS);

        split_f16<<<4096, 256, 0, stream>>>(x, W1, Xh, Wh);
        fc1_f16<<<dim3(H_DIM / 128, B_ROWS / 256), 512, 0, stream>>>(
            Xh, Wh, x, W1, b1, bits);
        fc2w4<<<B_ROWS / 16, 256, 0, stream>>>(bits, W2, b2, out);
    } else {
        uint32_t* bits = (uint32_t*)ws;
        dim3 g1(H_DIM / BN, B_ROWS / BM);
        snn_fc1<<<g1, 256, 0, stream>>>(x, W1, b1, bits);
        fc2w4<<<B_ROWS / 16, 256, 0, stream>>>(bits, W2, b2, out);
    }
}

// Round 14
// 256.744 us; speedup vs baseline: 2.4799x; 1.0268x over previous
//
#include <hip/hip_runtime.h>
#include <cstdint>
#include <cstddef>

typedef __attribute__((ext_vector_type(8))) _Float16 f16x8;
typedef __attribute__((ext_vector_type(4))) float f32x4;

#define B_ROWS 16384
#define K_DIM  1024
#define H_DIM  4096
#define O_DIM  4
#define MARGIN 2.5e-3f         // 6.3 sigma of the f16 dot error (sigma~4e-4)
#define STASH_CAP 2048         // flags/block ~Poisson(80); 25x headroom

// ws layout (bytes)
#define OFF_XH   ((size_t)0)                 // 16384*1024*2 = 33554432
#define OFF_WH   ((size_t)33554432)          // 4096*1024*2  =  8388608
#define OFF_BITS ((size_t)41943040)          // 16384*128*4  =  8388608
#define WS_NEED  ((size_t)50331648)

#define GLD16(g, l) __builtin_amdgcn_global_load_lds(                         \
    (const __attribute__((address_space(1))) void*)(g),                       \
    (__attribute__((address_space(3))) void*)(l), 16, 0, 0)

// ---------------------------------------------------------------------------
// split: f32 -> f16 (RTN) for x and W1, fused.
// ---------------------------------------------------------------------------
__global__ __launch_bounds__(256) void split_f16(
    const float* __restrict__ x, const float* __restrict__ W1,
    _Float16* __restrict__ Xh, _Float16* __restrict__ Wh)
{
    const int NX8 = (B_ROWS * K_DIM) / 8;
    const int NW8 = (H_DIM * K_DIM) / 8;
    const int stride = gridDim.x * blockDim.x;
    for (int i = blockIdx.x * blockDim.x + threadIdx.x; i < NX8 + NW8; i += stride) {
        const float* src; _Float16* dst; int j;
        if (i < NX8) { src = x; dst = Xh; j = i; }
        else         { src = W1; dst = Wh; j = i - NX8; }
        const float4 f0 = reinterpret_cast<const float4*>(src)[2 * j];
        const float4 f1 = reinterpret_cast<const float4*>(src)[2 * j + 1];
        f16x8 h;
        h[0] = (_Float16)f0.x; h[1] = (_Float16)f0.y;
        h[2] = (_Float16)f0.z; h[3] = (_Float16)f0.w;
        h[4] = (_Float16)f1.x; h[5] = (_Float16)f1.y;
        h[6] = (_Float16)f1.z; h[7] = (_Float16)f1.w;
        reinterpret_cast<f16x8*>(dst)[j] = h;
    }
}

// ---------------------------------------------------------------------------
// fc1: 8-phase counted-vmcnt f16 MFMA GEMM (m201-style schedule derived with
// explicit WAR/RAW proof), 256x256 tile, BK=64, 8 waves (2M x 4N), 2 LDS
// dbufs (static indices). Chunk-XOR swizzle (r8-verified involution).
// FUSED exact f64 refine epilogue.
//
// Per iteration (2 K-tiles: dbuf0 = kt 2it, dbuf1 = kt 2it+1), 8 phases.
// Stage map (each stage issued AFTER its target region's last-read barrier):
//   ph0: A-dbuf1 (kt 2it+1, both halves)   [WAR: A-db1 last read prev ph7]
//   ph1: B-next h0 / ph2: B-next h1        [WAR: B-db0 last read ph0]
//   ph4: A-next h0 / ph5: A-next h1        [WAR: A-db0 last read ph3]
//   ph6: B-next2 h0 / ph7: B-next2 h1      [WAR: B-db1 last read ph4]
// vmcnt(4) at ph3/ph7 ends: leaves only the 2 newest half-tiles in flight ->
//   ph3: A-db1(ph0) + B-db1(prev ph6/7) landed before ph4 reads  [RAW]
//   ph7: A-next(ph4/5) + B-next(ph1/2) landed before next ph0    [RAW]
// ---------------------------------------------------------------------------
#define BAR    __builtin_amdgcn_s_barrier()
#define LGKM0  asm volatile("s_waitcnt lgkmcnt(0)" ::: "memory")
#define VMC4   asm volatile("s_waitcnt vmcnt(4)" ::: "memory")
#define VMC0   asm volatile("s_waitcnt vmcnt(0)" ::: "memory")
#define PRIO1  __builtin_amdgcn_s_setprio(1)
#define PRIO0  __builtin_amdgcn_s_setprio(0)

#define RDA(DB, Q, AFR) do {                                                  \
  _Pragma("unroll") for (int i_ = 0; i_ < 2; ++i_)                            \
  _Pragma("unroll") for (int kk_ = 0; kk_ < 2; ++kk_) {                       \
    const int row_ = (wm << 7) + ((Q) * 2 + i_) * 16 + frow;                  \
    const int ch_  = (kk_ * 4 + fkc) ^ ((row_ >> 1) & 7);                     \
    AFR[i_][kk_] = *reinterpret_cast<const f16x8*>(                           \
        &As[DB][row_ * 64 + ch_ * 8]); }                                      \
} while (0)

#define RDB(DB, BFR) do {                                                     \
  _Pragma("unroll") for (int nj_ = 0; nj_ < 4; ++nj_)                         \
  _Pragma("unroll") for (int kk_ = 0; kk_ < 2; ++kk_) {                       \
    const int row_ = (wn << 6) + nj_ * 16 + frow;                             \
    const int ch_  = (kk_ * 4 + fkc) ^ ((row_ >> 1) & 7);                     \
    BFR[nj_][kk_] = *reinterpret_cast<const f16x8*>(                          \
        &Bs[DB][row_ * 64 + ch_ * 8]); }                                      \
} while (0)

#define MM16(Q, AFR, BFR) do {                                                \
  _Pragma("unroll") for (int i_ = 0; i_ < 2; ++i_)                            \
  _Pragma("unroll") for (int nj_ = 0; nj_ < 4; ++nj_)                         \
  _Pragma("unroll") for (int kk_ = 0; kk_ < 2; ++kk_)                         \
    acc[(Q) * 2 + i_][nj_] = __builtin_amdgcn_mfma_f32_16x16x32_f16(          \
        AFR[i_][kk_], BFR[nj_][kk_], acc[(Q) * 2 + i_][nj_], 0, 0, 0);        \
} while (0)

__global__ __launch_bounds__(512, 2) void fc1_8ph(
    const _Float16* __restrict__ Xh, const _Float16* __restrict__ Wh,
    const float* __restrict__ xf, const float* __restrict__ w1f,
    const float* __restrict__ b1, uint32_t* __restrict__ bits)
{
    __shared__ __align__(16) _Float16 As[2][256 * 64];   // 64 KB
    __shared__ __align__(16) _Float16 Bs[2][256 * 64];   // 64 KB
    __shared__ uint32_t scnt;

    const int tid  = threadIdx.x;
    const int lane = tid & 63;
    const int w    = tid >> 6;          // 0..7
    const int wm   = w >> 2;            // 0..1 (M half)
    const int wn   = w & 3;             // 0..3 (N quarter)
    const int m0   = blockIdx.y * 256;
    const int n0   = blockIdx.x * 256;
    const int frow = lane & 15;
    const int fkc  = lane >> 4;

    // staging: one GLD16 call covers 64 rows x 64 halfs; thread -> row/chunk.
    // Global chunk inverse-swizzled (ch ^= (row>>1)&7); LDS dest linear.
    const int sr8 = (w << 3) + (lane >> 3);   // 0..63 within call
    const int sc  = lane & 7;

    auto stA = [&](int db, int kt, int half) {
#pragma unroll
        for (int c = 0; c < 2; ++c) {
            const int rw  = half * 128 + c * 64 + sr8;
            const int gch = sc ^ ((rw >> 1) & 7);
            GLD16(Xh + (size_t)(m0 + rw) * K_DIM + kt * 64 + gch * 8,
                  &As[db][(half * 128 + c * 64 + (w << 3)) * 64]);
        }
    };
    auto stB = [&](int db, int kt, int half) {
#pragma unroll
        for (int c = 0; c < 2; ++c) {
            const int rw  = half * 128 + c * 64 + sr8;
            const int gch = sc ^ ((rw >> 1) & 7);
            GLD16(Wh + (size_t)(n0 + rw) * K_DIM + kt * 64 + gch * 8,
                  &Bs[db][(half * 128 + c * 64 + (w << 3)) * 64]);
        }
    };

    f32x4 acc[8][4];
#pragma unroll
    for (int i = 0; i < 8; ++i)
#pragma unroll
        for (int j = 0; j < 4; ++j)
            acc[i][j] = (f32x4){0.f, 0.f, 0.f, 0.f};

    // prologue: K-tile0 (A+B) + K-tile1's B; wait all but newest 2 half-tiles
    stA(0, 0, 0); stA(0, 0, 1); stB(0, 0, 0); stB(0, 0, 1);
    stB(1, 1, 0); stB(1, 1, 1);
    VMC4; BAR;

#pragma unroll 1
    for (int it = 0; it < 8; ++it) {
        const int ktA1 = 2 * it + 1, ktN = 2 * it + 2, ktN2 = 2 * it + 3;
        const bool more = (it < 7);
        f16x8 bfr[4][2], afr[2][2];

        // ---- phase 0 (dbuf0, q0) ----
        RDB(0, bfr); RDA(0, 0, afr);
        stA(1, ktA1, 0); stA(1, ktA1, 1);
        BAR; LGKM0; PRIO1; MM16(0, afr, bfr); PRIO0; BAR;
        // ---- phase 1 (q1) ----
        RDA(0, 1, afr); if (more) stB(0, ktN, 0);
        BAR; LGKM0; PRIO1; MM16(1, afr, bfr); PRIO0; BAR;
        // ---- phase 2 (q2) ----
        RDA(0, 2, afr); if (more) stB(0, ktN, 1);
        BAR; LGKM0; PRIO1; MM16(2, afr, bfr); PRIO0; BAR;
        // ---- phase 3 (q3) ----
        RDA(0, 3, afr);
        BAR; LGKM0; PRIO1; MM16(3, afr, bfr); PRIO0; VMC4; BAR;
        // ---- phase 4 (dbuf1, q0) ----
        RDB(1, bfr); RDA(1, 0, afr); if (more) stA(0, ktN, 0);
        BAR; LGKM0; PRIO1; MM16(0, afr, bfr); PRIO0; BAR;
        // ---- phase 5 (q1) ----
        RDA(1, 1, afr); if (more) stA(0, ktN, 1);
        BAR; LGKM0; PRIO1; MM16(1, afr, bfr); PRIO0; BAR;
        // ---- phase 6 (q2) ----
        RDA(1, 2, afr); if (more) stB(1, ktN2, 0);
        BAR; LGKM0; PRIO1; MM16(2, afr, bfr); PRIO0; BAR;
        // ---- phase 7 (q3) ----
        RDA(1, 3, afr); if (more) stB(1, ktN2, 1);
        BAR; LGKM0; PRIO1; MM16(3, afr, bfr); PRIO0;
        if (more) { VMC4; } else { VMC0; }
        BAR;
    }

    // ---- epilogue pass 1: ballot words -> LDS bitbuf, flags -> LDS stash ----
    __syncthreads();                           // staged data dead; reuse LDS
    uint32_t* stash  = (uint32_t*)&As[0][0];
    uint32_t* bitbuf = (uint32_t*)&Bs[0][0];   // 256 rows x 8 words = 8 KB
    if (tid == 0) scnt = 0u;
    __syncthreads();

    float bcol[4];
#pragma unroll
    for (int nj = 0; nj < 4; ++nj) bcol[nj] = b1[n0 + (wn << 6) + nj * 16 + frow];

    const int g = lane >> 4;
#pragma unroll
    for (int mi = 0; mi < 8; ++mi) {
#pragma unroll
        for (int r = 0; r < 4; ++r) {
            unsigned long long bj[4];
#pragma unroll
            for (int nj = 0; nj < 4; ++nj) {
                const float cur_v = acc[mi][nj][r] + bcol[nj];
                bj[nj] = __ballot(cur_v > 1.0f);
                if (fabsf(cur_v - 1.0f) < MARGIN) {
                    const uint32_t enc =
                        ((uint32_t)((wm << 7) + mi * 16 + g * 4 + r) << 8)
                      | (uint32_t)((wn << 6) + nj * 16 + frow);
                    uint32_t ix = atomicAdd(&scnt, 1u);
                    if (ix < STASH_CAP) stash[ix] = enc;
                }
            }
            if (frow == 0) {
                const int row_l = (wm << 7) + mi * 16 + g * 4 + r;  // 0..255
                const uint32_t w0 =
                    (uint32_t)((bj[0] >> (g * 16)) & 0xFFFFull) |
                    ((uint32_t)((bj[1] >> (g * 16)) & 0xFFFFull) << 16);
                const uint32_t w1 =
                    (uint32_t)((bj[2] >> (g * 16)) & 0xFFFFull) |
                    ((uint32_t)((bj[3] >> (g * 16)) & 0xFFFFull) << 16);
                uint2 v; v.x = w0; v.y = w1;
                *reinterpret_cast<uint2*>(&bitbuf[row_l * 8 + (wn << 1)]) = v;
            }
        }
    }
    __syncthreads();

    // ---- epilogue pass 2: in-block exact f64 refine (wave per flag) ----
    const uint32_t nf = (scnt < STASH_CAP) ? scnt : STASH_CAP;
    for (uint32_t f = (uint32_t)w; f < nf; f += 8) {
        const uint32_t e = stash[f];
        const int row_l = (int)(e >> 8), col_l = (int)(e & 255);
        const float4* xr  = (const float4*)(xf  + (size_t)(m0 + row_l) * K_DIM);
        const float4* wr2 = (const float4*)(w1f + (size_t)(n0 + col_l) * K_DIM);
        double s = 0.0;
#pragma unroll
        for (int i = 0; i < 4; ++i) {
            const float4 xa = xr[lane + i * 64];
            const float4 wa = wr2[lane + i * 64];
            s = fma((double)xa.x, (double)wa.x, s);
            s = fma((double)xa.y, (double)wa.y, s);
            s = fma((double)xa.z, (double)wa.z, s);
            s = fma((double)xa.w, (double)wa.w, s);
        }
        for (int off = 32; off; off >>= 1) s += __shfl_down(s, off, 64);
        if (lane == 0) {
            const double cur_v = s + (double)b1[n0 + col_l];
            uint32_t* word = &bitbuf[row_l * 8 + (col_l >> 5)];
            const uint32_t mask = 1u << (col_l & 31);
            if (cur_v > 1.0) atomicOr(word, mask);
            else             atomicAnd(word, ~mask);
        }
    }
    __syncthreads();

    // ---- epilogue pass 3: coalesced store, each word exactly once ----
    {
        const int row = tid >> 1, qw = tid & 1;
        const uint4 v = *reinterpret_cast<const uint4*>(&bitbuf[row * 8 + qw * 4]);
        *reinterpret_cast<uint4*>(
            &bits[(size_t)(m0 + row) * 128 + (n0 >> 5) + qw * 4]) = v;
    }
}

// ---------------------------------------------------------------------------
// fc2: one wave per 4 batch rows (W2 loads reused 4x, fits registers).
// ---------------------------------------------------------------------------
__global__ __launch_bounds__(256) void fc2w4(
    const uint32_t* __restrict__ bits, const float* __restrict__ W2,
    const float* __restrict__ b2, float* __restrict__ out)
{
    const int lane = threadIdx.x & 63;
    const int rb   = (blockIdx.x * 4 + (threadIdx.x >> 6)) * 4;  // row base
    uint32_t w0[4], w1[4];
#pragma unroll
    for (int rr = 0; rr < 4; ++rr) {
        const uint2 v = *reinterpret_cast<const uint2*>(
            &bits[(size_t)(rb + rr) * 128 + 2 * lane]);
        w0[rr] = v.x; w1[rr] = v.y;
    }
    double acc[4][4];
#pragma unroll
    for (int rr = 0; rr < 4; ++rr)
#pragma unroll
        for (int o = 0; o < 4; ++o) acc[rr][o] = 0.0;

#pragma unroll
    for (int o = 0; o < 4; ++o) {
        const float4* wrow = (const float4*)(W2 + (size_t)o * H_DIM + lane * 64);
#pragma unroll
        for (int q = 0; q < 16; ++q) {
            const float4 v = wrow[q];
            const int bit = (4 * q) & 31;
#pragma unroll
            for (int rr = 0; rr < 4; ++rr) {
                const uint32_t word = (q < 8) ? w0[rr] : w1[rr];
                if ((word >> bit)       & 1u) acc[rr][o] += (double)v.x;
                if ((word >> (bit + 1)) & 1u) acc[rr][o] += (double)v.y;
                if ((word >> (bit + 2)) & 1u) acc[rr][o] += (double)v.z;
                if ((word >> (bit + 3)) & 1u) acc[rr][o] += (double)v.w;
            }
        }
    }
#pragma unroll
    for (int off = 32; off; off >>= 1)
#pragma unroll
        for (int rr = 0; rr < 4; ++rr)
#pragma unroll
            for (int o = 0; o < 4; ++o)
                acc[rr][o] += __shfl_down(acc[rr][o], off, 64);
    if (lane == 0) {
#pragma unroll
        for (int rr = 0; rr < 4; ++rr)
#pragma unroll
            for (int o = 0; o < 4; ++o) {
                const double cur = acc[rr][o] + (double)b2[o];
                out[(rb + rr) * 4 + o] = (float)cur;
                out[B_ROWS * O_DIM + (rb + rr) * 4 + o] = (cur > 1.0) ? 1.0f : 0.0f;
            }
    }
}

// ---------------------------------------------------------------------------
// Fallback exact-f64 fc1 (round-1 kernel) for small ws_size
// ---------------------------------------------------------------------------
#define BM 64
#define BN 64
#define BK 32
__global__ __launch_bounds__(256) void snn_fc1(
    const float* __restrict__ x, const float* __restrict__ W1,
    const float* __restrict__ b1, uint32_t* __restrict__ spk_bits)
{
    __shared__ float As[BK][68];
    __shared__ float Bs[BK][68];
    __shared__ uint32_t bitbuf[BM][BN / 32];

    const int tid = threadIdx.x;
    const int m0 = blockIdx.y * BM;
    const int n0 = blockIdx.x * BN;
    const int rm = tid & 15, cn = tid >> 4;
    const int mf = 4 * rm, nf = 4 * cn;

    double acc[4][4];
#pragma unroll
    for (int i = 0; i < 4; ++i)
#pragma unroll
        for (int j = 0; j < 4; ++j) acc[i][j] = 0.0;

    const int sm = tid >> 3, skq = tid & 7;
    for (int kt = 0; kt < K_DIM / BK; ++kt) {
        const int k0 = kt * BK;
#pragma unroll
        for (int s = 0; s < 2; ++s) {
            const int m = sm + 32 * s;
            const float4 av = *reinterpret_cast<const float4*>(
                x + (size_t)(m0 + m) * K_DIM + k0 + 4 * skq);
            As[4 * skq + 0][m] = av.x; As[4 * skq + 1][m] = av.y;
            As[4 * skq + 2][m] = av.z; As[4 * skq + 3][m] = av.w;
            const float4 bv = *reinterpret_cast<const float4*>(
                W1 + (size_t)(n0 + m) * K_DIM + k0 + 4 * skq);
            Bs[4 * skq + 0][m] = bv.x; Bs[4 * skq + 1][m] = bv.y;
            Bs[4 * skq + 2][m] = bv.z; Bs[4 * skq + 3][m] = bv.w;
        }
        __syncthreads();
#pragma unroll
        for (int k = 0; k < BK; ++k) {
            const float4 af = *reinterpret_cast<const float4*>(&As[k][mf]);
            const float4 bf = *reinterpret_cast<const float4*>(&Bs[k][nf]);
            const double a0 = af.x, a1 = af.y, a2 = af.z, a3 = af.w;
            const double b0 = bf.x, b1v = bf.y, b2v = bf.z, b3 = bf.w;
            acc[0][0] = fma(a0, b0, acc[0][0]);  acc[0][1] = fma(a0, b1v, acc[0][1]);
            acc[0][2] = fma(a0, b2v, acc[0][2]); acc[0][3] = fma(a0, b3, acc[0][3]);
            acc[1][0] = fma(a1, b0, acc[1][0]);  acc[1][1] = fma(a1, b1v, acc[1][1]);
            acc[1][2] = fma(a1, b2v, acc[1][2]); acc[1][3] = fma(a1, b3, acc[1][3]);
            acc[2][0] = fma(a2, b0, acc[2][0]);  acc[2][1] = fma(a2, b1v, acc[2][1]);
            acc[2][2] = fma(a2, b2v, acc[2][2]); acc[2][3] = fma(a2, b3, acc[2][3]);
            acc[3][0] = fma(a3, b0, acc[3][0]);  acc[3][1] = fma(a3, b1v, acc[3][1]);
            acc[3][2] = fma(a3, b2v, acc[3][2]); acc[3][3] = fma(a3, b3, acc[3][3]);
        }
        __syncthreads();
    }

    if (tid < BM * (BN / 32)) bitbuf[tid >> 1][tid & 1] = 0u;
    __syncthreads();
#pragma unroll
    for (int j = 0; j < 4; ++j) {
        const int n = nf + j;
        const double bias = (double)b1[n0 + n];
        const int wd = n >> 5, bit = n & 31;
#pragma unroll
        for (int i = 0; i < 4; ++i) {
            const double cur = acc[i][j] + bias;
            if (cur > 1.0) atomicOr(&bitbuf[mf + i][wd], 1u << bit);
        }
    }
    __syncthreads();
    if (tid < 128) {
        const int r = tid >> 1, wd = tid & 1;
        spk_bits[(size_t)(m0 + r) * (H_DIM / 32) + (n0 >> 5) + wd] = bitbuf[r][wd];
    }
}

// ---------------------------------------------------------------------------
extern "C" void kernel_launch(void* const* d_in, const int* in_sizes, int n_in,
                              void* d_out, int out_size, void* d_ws, size_t ws_size,
                              hipStream_t stream) {
    const float* x  = (const float*)d_in[0];
    const float* W1 = (const float*)d_in[1];
    const float* b1 = (const float*)d_in[2];
    const float* W2 = (const float*)d_in[3];
    const float* b2 = (const float*)d_in[4];
    float* out = (float*)d_out;
    char* ws = (char*)d_ws;

    if (ws_size >= WS_NEED) {
        _Float16* Xh   = (_Float16*)(ws + OFF_XH);
        _Float16* Wh   = (_Float16*)(ws + OFF_WH);
        uint32_t* bits = (uint32_t*)(ws + OFF_BITS);

        split_f16<<<4096, 256, 0, stream>>>(x, W1, Xh, Wh);
        fc1_8ph<<<dim3(H_DIM / 256, B_ROWS / 256), 512, 0, stream>>>(
            Xh, Wh, x, W1, b1, bits);
        fc2w4<<<B_ROWS / 16, 256, 0, stream>>>(bits, W2, b2, out);
    } else {
        uint32_t* bits = (uint32_t*)ws;
        dim3 g1(H_DIM / BN, B_ROWS / BM);
        snn_fc1<<<g1, 256, 0, stream>>>(x, W1, b1, bits);
        fc2w4<<<B_ROWS / 16, 256, 0, stream>>>(bits, W2, b2, out);
    }
}